// Round 4
// baseline (94.775 us; speedup 1.0000x reference)
//
#include <hip/hip_runtime.h>
#include <cfloat>

// BottomPool: out[b,c,h,w] = max_{h'<=h} x[b,c,h',w]
// x: (16, 256, 128, 128) fp32 contiguous, W innermost.
//
// Barrier-free segmented scan. One wave owns an 8-column (128B-wide) slab of
// one (b,c) image: lane = s*8 + col8 covers 8 H-segments x 8 f4-columns.
// Each lane: 16 independent nontemporal loads, register cummax, then an
// exclusive prefix-max over the 8 segments via stride-8 __shfl_up (in-wave,
// no LDS, no __syncthreads), apply + nontemporal store. Each wave streams
// independently -> loads/stores interleave instead of phase-bursting.

#define H_DIM 128
#define W4_DIM 32   // W=128 floats / 4
#define SEG 16      // rows per thread
#define NSEG 8      // H_DIM / SEG

typedef float f4 __attribute__((ext_vector_type(4)));

__device__ __forceinline__ f4 f4max(f4 a, f4 b) {
    f4 r;
    r.x = fmaxf(a.x, b.x);
    r.y = fmaxf(a.y, b.y);
    r.z = fmaxf(a.z, b.z);
    r.w = fmaxf(a.w, b.w);
    return r;
}

__device__ __forceinline__ f4 f4shfl_up(f4 a, int d) {
    f4 r;
    r.x = __shfl_up(a.x, d, 64);
    r.y = __shfl_up(a.y, d, 64);
    r.z = __shfl_up(a.z, d, 64);
    r.w = __shfl_up(a.w, d, 64);
    return r;
}

__global__ __launch_bounds__(256) void bottom_pool_kernel(
    const f4* __restrict__ x, f4* __restrict__ out) {
    int tid  = threadIdx.x;
    int lane = tid & 63;
    int wv   = tid >> 6;          // wave 0..3 = column-slab within the image
    int col8 = lane & 7;          // f4-column within the slab
    int s    = lane >> 3;         // H-segment 0..7

    int col  = wv * 8 + col8;     // f4 column 0..31
    int base = blockIdx.x * (H_DIM * W4_DIM) + s * (SEG * W4_DIM) + col;

    // 1) 16 independent nontemporal loads (8 aligned 128B chunks per instr)
    f4 v[SEG];
#pragma unroll
    for (int j = 0; j < SEG; ++j)
        v[j] = __builtin_nontemporal_load(&x[base + j * W4_DIM]);

    // 2) local inclusive cummax within the segment
#pragma unroll
    for (int j = 1; j < SEG; ++j) v[j] = f4max(v[j], v[j - 1]);

    // 3) in-wave inclusive scan of segment maxima over s (stride-8 lanes),
    //    then shift by one segment for the exclusive prefix
    f4 m = v[SEG - 1];
#pragma unroll
    for (int d = 8; d < 64; d <<= 1) {
        f4 t = f4shfl_up(m, d);
        if (lane >= d) m = f4max(m, t);
    }
    f4 p = f4shfl_up(m, 8);
    if (s == 0) p = f4{-FLT_MAX, -FLT_MAX, -FLT_MAX, -FLT_MAX};

    // 4) apply prefix, nontemporal store (fire-and-forget, no barrier)
#pragma unroll
    for (int j = 0; j < SEG; ++j)
        __builtin_nontemporal_store(f4max(p, v[j]), &out[base + j * W4_DIM]);
}

extern "C" void kernel_launch(void* const* d_in, const int* in_sizes, int n_in,
                              void* d_out, int out_size, void* d_ws, size_t ws_size,
                              hipStream_t stream) {
    const f4* x = (const f4*)d_in[0];
    f4* out = (f4*)d_out;

    int n_images = out_size / (H_DIM * W4_DIM * 4);  // B*C = 4096
    bottom_pool_kernel<<<n_images, 256, 0, stream>>>(x, out);
}

// Round 5
// 91.516 us; speedup vs baseline: 1.0356x; 1.0356x over previous
//
#include <hip/hip_runtime.h>
#include <cfloat>

// BottomPool: out[b,c,h,w] = max_{h'<=h} x[b,c,h',w]
// x: (16, 256, 128, 128) fp32 contiguous, W innermost.
//
// Segmented scan, one block per (b,c) image: 256 threads = 32 float4-columns
// x 8 H-segments of 16 rows. 16 independent nontemporal loads per thread,
// register cummax, LDS exchange of segment maxima, exclusive prefix-max,
// apply + nontemporal store. Traffic = exactly 1 read + 1 write per element.
// (Round-4 barrier-free shfl variant regressed: fragmented coalescing +
// cross-lane scan on the critical path. This LDS version is the best: 91.5us
// = 5.87 TB/s = 93% of the measured 1R+1W copy ceiling.)

#define H_DIM 128
#define W4_DIM 32   // W=128 floats / 4
#define SEG 16      // rows per thread
#define NSEG 8      // H_DIM / SEG

typedef float f4 __attribute__((ext_vector_type(4)));

__device__ __forceinline__ f4 f4max(f4 a, f4 b) {
    f4 r;
    r.x = fmaxf(a.x, b.x);
    r.y = fmaxf(a.y, b.y);
    r.z = fmaxf(a.z, b.z);
    r.w = fmaxf(a.w, b.w);
    return r;
}

__global__ __launch_bounds__(256) void bottom_pool_kernel(
    const f4* __restrict__ x, f4* __restrict__ out) {
    __shared__ f4 smax[NSEG][W4_DIM];

    int tid = threadIdx.x;
    int col = tid & (W4_DIM - 1);  // float4 column within the row
    int s   = tid >> 5;            // segment index 0..7

    // 32-bit offsets: max index = 4096 images * 4096 f4 = 2^24, fits easily.
    int base = blockIdx.x * (H_DIM * W4_DIM) + s * (SEG * W4_DIM) + col;

    // 1) 16 independent, coalesced, nontemporal loads
    f4 v[SEG];
#pragma unroll
    for (int j = 0; j < SEG; ++j)
        v[j] = __builtin_nontemporal_load(&x[base + j * W4_DIM]);

    // 2) local inclusive cummax within the segment
#pragma unroll
    for (int j = 1; j < SEG; ++j) v[j] = f4max(v[j], v[j - 1]);

    // 3) publish segment max; exclusive prefix-max over earlier segments
    smax[s][col] = v[SEG - 1];
    __syncthreads();

    f4 p = {-FLT_MAX, -FLT_MAX, -FLT_MAX, -FLT_MAX};
    for (int t = 0; t < s; ++t) p = f4max(p, smax[t][col]);

    // 4) apply prefix, nontemporal store (fire-and-forget)
#pragma unroll
    for (int j = 0; j < SEG; ++j)
        __builtin_nontemporal_store(f4max(p, v[j]), &out[base + j * W4_DIM]);
}

extern "C" void kernel_launch(void* const* d_in, const int* in_sizes, int n_in,
                              void* d_out, int out_size, void* d_ws, size_t ws_size,
                              hipStream_t stream) {
    const f4* x = (const f4*)d_in[0];
    f4* out = (f4*)d_out;

    int n_images = out_size / (H_DIM * W4_DIM * 4);  // B*C = 4096
    bottom_pool_kernel<<<n_images, 256, 0, stream>>>(x, out);
}